// Round 10
// baseline (218.089 us; speedup 1.0000x reference)
//
#include <hip/hip_runtime.h>
#include <cstdint>

// ConvBnA int8 conv via i8 MFMA (exact: i32 accumulation).
// Pass 1 (fused): x NCHW int32 -> int8 NHWC (reg-only transpose) AND
//                 weight int32 [co][ci][3][3] -> int8 [g][co][ci] (+ zero page)
// Pass 2 : implicit GEMM, r3 sync skeleton, BK=128/tap, 128x128 tile, 4 waves.
//          A (weights, L2-hot) in REGISTERS with 1-step prefetch (aE/aO
//          double-buffer, static indexing); B-only LDS (2x16KB).
//          Counted vmcnt(12) keeps the 12 prefetch loads (8 A + 4 B) in
//          flight while draining step-s operands. 32-MFMA clusters.
// Output: harness reads integer outputs as int32 -> store int.

typedef __attribute__((ext_vector_type(4))) int i32x4;
typedef __attribute__((ext_vector_type(2))) int i32x2;

#define C_IN   128
#define HW2    3136      // 56*56
#define OUT_NSTRIDE 802816  // 256*3136

// workspace layout (bytes)
#define XQ_BYTES 12845056            // 100352 * 128 int8
#define WQ_OFF   XQ_BYTES
#define WQ_BYTES 294912              // 9*256*128 int8
#define ZP_OFF   (WQ_OFF + WQ_BYTES) // 256 zero bytes (16B-aligned)

__device__ __forceinline__ void gload_lds16(const void* g, void* l) {
  __builtin_amdgcn_global_load_lds(
      (const __attribute__((address_space(1))) void*)(uintptr_t)g,
      (__attribute__((address_space(3))) void*)(uint32_t)(uintptr_t)l,
      16, 0, 0);
}

// ---------------- pass 1 (fused): x transpose + weight pack ----------------
__global__ __launch_bounds__(256) void prep(const int* __restrict__ x,
                                            const int* __restrict__ w,
                                            char* __restrict__ xq,
                                            char* __restrict__ wq,
                                            int* __restrict__ zp) {
  int bid = blockIdx.x;
  if (bid >= 1568) {                    // weight pack: blocks 1568..2719
    int id = (bid - 1568) * 256 + threadIdx.x;   // over 9*256*128 = 294912
    int ci = id & 127;
    int co = (id >> 7) & 255;
    int g  = id >> 15;                  // kh*3+kw
    wq[id] = (char)w[co * 1152 + ci * 9 + g];
    if (bid == 1568 && threadIdx.x < 64) zp[threadIdx.x] = 0;
    return;
  }
  // x transpose: blocks 0..1567 (32n * 49hb)
  int hb = bid % 49;
  int n  = bid / 49;
  int t  = threadIdx.x;
  int cig = t & 15;                     // ci group (8 ci each)
  int hw0 = (t >> 4) * 4;               // 4 pixels
  const int* src = x + n * (C_IN * HW2) + hb * 64 + hw0;
  i32x4 ld[8];
#pragma unroll
  for (int j = 0; j < 8; j++)
    ld[j] = *(const i32x4*)(src + (cig * 8 + j) * HW2);
  char* dst = xq + (size_t)(n * HW2 + hb * 64 + hw0) * 128 + cig * 8;
#pragma unroll
  for (int p = 0; p < 4; p++) {
    unsigned lo = (ld[0][p] & 255) | ((ld[1][p] & 255) << 8) |
                  ((ld[2][p] & 255) << 16) | ((unsigned)(ld[3][p] & 255) << 24);
    unsigned hi = (ld[4][p] & 255) | ((ld[5][p] & 255) << 8) |
                  ((ld[6][p] & 255) << 16) | ((unsigned)(ld[7][p] & 255) << 24);
    i32x2 v; v[0] = (int)lo; v[1] = (int)hi;
    *(i32x2*)(dst + p * 128) = v;
  }
}

// ---------------- pass 2: i8 MFMA implicit GEMM, A-in-regs prefetched ----------------
__global__ __launch_bounds__(256, 2) void conv_mfma(
    const char* __restrict__ xq, const char* __restrict__ wq,
    const char* __restrict__ zp,
    const int* __restrict__ nshift, const int* __restrict__ tbias,
    const int* __restrict__ aminp, const int* __restrict__ amaxp,
    int* __restrict__ out) {
  __shared__ char lds[32768];   // 2 B-bufs x 16KB; row = 128B (128 ci int8)

  const int tid = threadIdx.x;
  const int bid = blockIdx.x;
  const int bm = bid & 1;        // co block (0..1)
  const int pb = bid >> 1;       // pixel block (0..783)
  const int l  = tid & 63;
  const int wid = tid >> 6;
  const int wm = wid >> 1, wn = wid & 1;   // 2x2 waves, 64x64 each

  // B staging: slot j = tid + i*256; row = j>>3 (0..127), local chunk = j&7 (16B)
  // swizzle: local chunk chl holds global chunk chl ^ (row&7)
  const int chl = tid & 7;
  const int rsw = (tid >> 3) & 7;          // row&7, invariant in i (i*32)
  const int chg = chl ^ rsw;
  const int kboff = chg * 16;              // byte offset within 128B row

  int p_idx[4], p_h[4], p_w[4];
#pragma unroll
  for (int i = 0; i < 4; i++) {
    int pr = (tid >> 3) + i * 32;
    int p  = pb * 128 + pr;
    int n  = p / HW2;
    int hw = p - n * HW2;
    int h  = hw / 56;
    int w  = hw - h * 56;
    p_idx[i] = p; p_h[i] = h; p_w[i] = w;
  }

  auto stageB = [&](int g, int buf) {
    char* Bb = lds + buf * 16384;
    const int dh = g / 3 - 1, dw = g % 3 - 1;
    const int doff = dh * 56 + dw;
#pragma unroll
    for (int i = 0; i < 4; i++) {
      int h2 = p_h[i] + dh, w2 = p_w[i] + dw;
      bool valid = ((unsigned)h2 < 56u) && ((unsigned)w2 < 56u);
      const char* gp = valid ? (xq + ((size_t)(p_idx[i] + doff) << 7) + kboff)
                             : zp;
      gload_lds16(gp, Bb + (tid + i * 256) * 16);
    }
  };

  i32x4 acc[4][4] = {};
  const int lrow = l & 15;
  const int lk   = (l >> 4) * 16;          // byte offset of lane's k-chunk
  const int lsw  = (l & 7) << 4;           // read-side swizzle XOR (row&7 == l&7)

  // per-lane A base: row = bm*128 + wm*64 + mi*16 + lrow, col = kk*64 + (l>>4)*16
  const char* abase = wq + (size_t)((bm * 128 + wm * 64 + lrow) << 7) + lk;

  i32x4 aE[8], aO[8];   // [kk*4+mi]; named double-buffer (static indexing)

#define ALOAD(s, dst) do {                                         \
    const char* ap_ = abase + (s) * 32768;                         \
    dst[0] = *(const i32x4*)(ap_ + 0 * 2048);                      \
    dst[1] = *(const i32x4*)(ap_ + 1 * 2048);                      \
    dst[2] = *(const i32x4*)(ap_ + 2 * 2048);                      \
    dst[3] = *(const i32x4*)(ap_ + 3 * 2048);                      \
    dst[4] = *(const i32x4*)(ap_ + 0 * 2048 + 64);                 \
    dst[5] = *(const i32x4*)(ap_ + 1 * 2048 + 64);                 \
    dst[6] = *(const i32x4*)(ap_ + 2 * 2048 + 64);                 \
    dst[7] = *(const i32x4*)(ap_ + 3 * 2048 + 64);                 \
  } while (0)

#define COMPUTE(s, areg) do {                                      \
    char* Bb_ = lds + ((s) & 1) * 16384;                           \
    _Pragma("unroll")                                              \
    for (int kk = 0; kk < 2; kk++) {                               \
      i32x4 b[4];                                                  \
      const int cb = ((kk * 64 + lk) ^ lsw);                       \
      _Pragma("unroll")                                            \
      for (int ni = 0; ni < 4; ni++) {                             \
        int row = wn * 64 + ni * 16 + lrow;                        \
        b[ni] = *(const i32x4*)(Bb_ + (row << 7) + cb);            \
      }                                                            \
      __builtin_amdgcn_s_setprio(1);                               \
      _Pragma("unroll")                                            \
      for (int mi = 0; mi < 4; mi++)                               \
        _Pragma("unroll")                                          \
        for (int ni = 0; ni < 4; ni++)                             \
          acc[mi][ni] = __builtin_amdgcn_mfma_i32_16x16x64_i8(     \
              areg[kk * 4 + mi], b[ni], acc[mi][ni], 0, 0, 0);     \
      __builtin_amdgcn_s_setprio(0);                               \
    }                                                              \
  } while (0)

  // prologue: step 0 operands in flight (B0: 4 gload_lds, A0: 8 reg loads)
  stageB(0, 0);
  ALOAD(0, aE);

#pragma unroll 1
  for (int sp = 0; sp < 9; sp += 2) {
    // ---- even step s = sp (uses aE), prefetch s+1 into aO ----
    if (sp + 1 < 9) { stageB(sp + 1, (sp + 1) & 1); ALOAD(sp + 1, aO); }
    __builtin_amdgcn_sched_barrier(0);
    if (sp + 1 < 9) { asm volatile("s_waitcnt vmcnt(12)" ::: "memory"); }
    else            { asm volatile("s_waitcnt vmcnt(0)"  ::: "memory"); }
    __builtin_amdgcn_s_barrier();
    __builtin_amdgcn_sched_barrier(0);
    COMPUTE(sp, aE);
    __builtin_amdgcn_sched_barrier(0);
    __builtin_amdgcn_s_barrier();
    __builtin_amdgcn_sched_barrier(0);
    // ---- odd step s = sp+1 (uses aO), prefetch s+2 into aE ----
    if (sp + 1 < 9) {
      if (sp + 2 < 9) { stageB(sp + 2, (sp + 2) & 1); ALOAD(sp + 2, aE); }
      __builtin_amdgcn_sched_barrier(0);
      if (sp + 2 < 9) { asm volatile("s_waitcnt vmcnt(12)" ::: "memory"); }
      else            { asm volatile("s_waitcnt vmcnt(0)"  ::: "memory"); }
      __builtin_amdgcn_s_barrier();
      __builtin_amdgcn_sched_barrier(0);
      COMPUTE(sp + 1, aO);
      __builtin_amdgcn_sched_barrier(0);
      __builtin_amdgcn_s_barrier();
      __builtin_amdgcn_sched_barrier(0);
    }
  }
#undef ALOAD
#undef COMPUTE

  // ---- epilogue: +t, >> (-n), clamp, store int32 ----
  const int amin = aminp[0], amax = amaxp[0];
  int pbase[4];
#pragma unroll
  for (int ni = 0; ni < 4; ni++) {
    int pp = pb * 128 + wn * 64 + ni * 16 + lrow;
    int nn = pp / HW2;
    int hh = pp - nn * HW2;
    pbase[ni] = nn * OUT_NSTRIDE + hh;
  }
#pragma unroll
  for (int mi = 0; mi < 4; mi++) {
    int co0 = bm * 128 + wm * 64 + mi * 16 + ((l >> 4) << 2);
    const int4 t4 = *(const int4*)(tbias + co0);
    const int4 n4 = *(const int4*)(nshift + co0);
#pragma unroll
    for (int ni = 0; ni < 4; ni++) {
#pragma unroll
      for (int r = 0; r < 4; r++) {
        int tv = (r == 0) ? t4.x : (r == 1) ? t4.y : (r == 2) ? t4.z : t4.w;
        int nv = (r == 0) ? n4.x : (r == 1) ? n4.y : (r == 2) ? n4.z : n4.w;
        int v = acc[mi][ni][r] + tv;
        v = v >> (-nv);                       // arithmetic shift
        v = v < amin ? amin : (v > amax ? amax : v);
        out[pbase[ni] + (co0 + r) * HW2] = v;
      }
    }
  }
}

extern "C" void kernel_launch(void* const* d_in, const int* in_sizes, int n_in,
                              void* d_out, int out_size, void* d_ws, size_t ws_size,
                              hipStream_t stream) {
  const int* x      = (const int*)d_in[0];
  const int* w      = (const int*)d_in[1];
  const int* nshift = (const int*)d_in[2];
  const int* tbias  = (const int*)d_in[3];
  const int* aminp  = (const int*)d_in[4];
  const int* amaxp  = (const int*)d_in[5];
  int* out = (int*)d_out;

  char* xq = (char*)d_ws;
  char* wq = (char*)d_ws + WQ_OFF;
  char* zp = (char*)d_ws + ZP_OFF;

  hipLaunchKernelGGL(prep, dim3(2720), dim3(256), 0, stream, x, w, xq, wq, (int*)zp);
  hipLaunchKernelGGL(conv_mfma, dim3(1568), dim3(256), 0, stream,
                     xq, wq, zp, nshift, tbias, aminp, amaxp, out);
}

// Round 11
// 180.891 us; speedup vs baseline: 1.2056x; 1.2056x over previous
//
#include <hip/hip_runtime.h>
#include <cstdint>

// ConvBnA int8 conv via i8 MFMA (exact: i32 accumulation).
// Pass 1 (fused): x NCHW int32 -> int8 NHWC (reg-only transpose) AND
//                 weight int32 [co][ci][3][3] -> int8 [g][co][ci] (+ zero page)
// Pass 2 : r8-verbatim conv (proven best): implicit GEMM, M=256, N=100352,
//          K=9*128, BK=128/tap (9 steps), 128x128 tile, 4 waves, 16x16x64 i8
//          MFMA, double-buffered 64KB LDS, gload_lds w=16, counted vmcnt(8),
//          XOR chunk-swizzle, 32-MFMA clusters between barrier pairs.
//          NEW vs r8: XCD-aware bijective block remap (1568 = 8 x 196) so
//          bm-pairs (same B-tile) + halo-neighbor pbs share one XCD L2.
// Output: harness reads integer outputs as int32 -> store int.

typedef __attribute__((ext_vector_type(4))) int i32x4;
typedef __attribute__((ext_vector_type(2))) int i32x2;

#define C_IN   128
#define HW2    3136      // 56*56
#define OUT_NSTRIDE 802816  // 256*3136

// workspace layout (bytes)
#define XQ_BYTES 12845056            // 100352 * 128 int8
#define WQ_OFF   XQ_BYTES
#define WQ_BYTES 294912              // 9*256*128 int8
#define ZP_OFF   (WQ_OFF + WQ_BYTES) // 256 zero bytes (16B-aligned)

__device__ __forceinline__ void gload_lds16(const void* g, void* l) {
  __builtin_amdgcn_global_load_lds(
      (const __attribute__((address_space(1))) void*)(uintptr_t)g,
      (__attribute__((address_space(3))) void*)(uint32_t)(uintptr_t)l,
      16, 0, 0);
}

// ---------------- pass 1 (fused): x transpose + weight pack ----------------
__global__ __launch_bounds__(256) void prep(const int* __restrict__ x,
                                            const int* __restrict__ w,
                                            char* __restrict__ xq,
                                            char* __restrict__ wq,
                                            int* __restrict__ zp) {
  int bid = blockIdx.x;
  if (bid >= 1568) {                    // weight pack: blocks 1568..2719
    int id = (bid - 1568) * 256 + threadIdx.x;   // over 9*256*128 = 294912
    int ci = id & 127;
    int co = (id >> 7) & 255;
    int g  = id >> 15;                  // kh*3+kw
    wq[id] = (char)w[co * 1152 + ci * 9 + g];
    if (bid == 1568 && threadIdx.x < 64) zp[threadIdx.x] = 0;
    return;
  }
  // x transpose: blocks 0..1567 (32n * 49hb)
  int hb = bid % 49;
  int n  = bid / 49;
  int t  = threadIdx.x;
  int cig = t & 15;                     // ci group (8 ci each)
  int hw0 = (t >> 4) * 4;               // 4 pixels
  const int* src = x + n * (C_IN * HW2) + hb * 64 + hw0;
  i32x4 ld[8];
#pragma unroll
  for (int j = 0; j < 8; j++)
    ld[j] = *(const i32x4*)(src + (cig * 8 + j) * HW2);
  char* dst = xq + (size_t)(n * HW2 + hb * 64 + hw0) * 128 + cig * 8;
#pragma unroll
  for (int p = 0; p < 4; p++) {
    unsigned lo = (ld[0][p] & 255) | ((ld[1][p] & 255) << 8) |
                  ((ld[2][p] & 255) << 16) | ((unsigned)(ld[3][p] & 255) << 24);
    unsigned hi = (ld[4][p] & 255) | ((ld[5][p] & 255) << 8) |
                  ((ld[6][p] & 255) << 16) | ((unsigned)(ld[7][p] & 255) << 24);
    i32x2 v; v[0] = (int)lo; v[1] = (int)hi;
    *(i32x2*)(dst + p * 128) = v;
  }
}

// ---------------- pass 2: i8 MFMA implicit GEMM (r8-verbatim + XCD remap) ----------------
__global__ __launch_bounds__(256, 2) void conv_mfma(
    const char* __restrict__ xq, const char* __restrict__ wq,
    const char* __restrict__ zp,
    const int* __restrict__ nshift, const int* __restrict__ tbias,
    const int* __restrict__ aminp, const int* __restrict__ amaxp,
    int* __restrict__ out) {
  __shared__ char lds[65536];   // 2 bufs x (A 16KB + B 16KB); row = 128B (128 ci int8)

  const int tid = threadIdx.x;
  const int bid = blockIdx.x;
  // XCD-aware bijective remap: 1568 = 8 XCD x 196. Dispatch round-robins
  // bid across XCDs; give each XCD a contiguous pb chunk of 98, with both
  // bm halves of each pb on the same XCD (B-tile fetched once per XCD).
  const int bm = (bid >> 3) & 1;           // co half (0..1)
  const int pb = (bid & 7) * 98 + (bid >> 4);  // pixel block (0..783)
  const int l  = tid & 63;
  const int wid = tid >> 6;
  const int wm = wid >> 1, wn = wid & 1;   // 2x2 waves, 64x64 each

  // staging: slot j = tid + i*256; row = j>>3 (0..127), local chunk = j&7 (16B)
  // swizzle: local chunk chl holds global chunk chl ^ (row&7)
  const int chl = tid & 7;
  const int rsw = (tid >> 3) & 7;          // row&7, invariant in i (i*32)
  const int chg = chl ^ rsw;
  const int kboff = chg * 16;              // byte offset within 128B row

  int p_idx[4], p_h[4], p_w[4];
#pragma unroll
  for (int i = 0; i < 4; i++) {
    int pr = (tid >> 3) + i * 32;
    int p  = pb * 128 + pr;
    int n  = p / HW2;
    int hw = p - n * HW2;
    int h  = hw / 56;
    int w  = hw - h * 56;
    p_idx[i] = p; p_h[i] = h; p_w[i] = w;
  }

  auto stageAB = [&](int g, int buf) {
    char* Ab = lds + buf * 32768;
    char* Bb = Ab + 16384;
    const int dh = g / 3 - 1, dw = g % 3 - 1;
    const int doff = dh * 56 + dw;
    // A: weight tile [co 128][ci 128] int8
    const char* wsrc = wq + (((g * 256 + bm * 128)) << 7) + kboff;
#pragma unroll
    for (int i = 0; i < 4; i++) {
      int row = (tid >> 3) + i * 32;
      gload_lds16(wsrc + (row << 7), Ab + (tid + i * 256) * 16);
    }
    // B: x tile [pix 128][ci 128] int8, zero-page redirect for halo
#pragma unroll
    for (int i = 0; i < 4; i++) {
      int h2 = p_h[i] + dh, w2 = p_w[i] + dw;
      bool valid = ((unsigned)h2 < 56u) && ((unsigned)w2 < 56u);
      const char* gp = valid ? (xq + ((size_t)(p_idx[i] + doff) << 7) + kboff)
                             : zp;
      gload_lds16(gp, Bb + (tid + i * 256) * 16);
    }
  };

  i32x4 acc[4][4] = {};
  const int lrow = l & 15;
  const int lk   = (l >> 4) * 16;          // byte offset of lane's k-chunk
  const int lsw  = (l & 7) << 4;           // read-side swizzle XOR (row&7 == l&7)

  auto computeStep = [&](int buf) {
    char* Ab = lds + buf * 32768;
    char* Bb = Ab + 16384;
#pragma unroll
    for (int kk = 0; kk < 2; kk++) {       // K=128 per tap = 2 x K64 MFMA
      i32x4 a[4], b[4];
      const int cb = ((kk * 64 + lk) ^ lsw);
#pragma unroll
      for (int mi = 0; mi < 4; mi++) {
        int row = wm * 64 + mi * 16 + lrow;
        a[mi] = *(const i32x4*)(Ab + (row << 7) + cb);
      }
#pragma unroll
      for (int ni = 0; ni < 4; ni++) {
        int row = wn * 64 + ni * 16 + lrow;
        b[ni] = *(const i32x4*)(Bb + (row << 7) + cb);
      }
#pragma unroll
      for (int mi = 0; mi < 4; mi++)
#pragma unroll
        for (int ni = 0; ni < 4; ni++)
          acc[mi][ni] = __builtin_amdgcn_mfma_i32_16x16x64_i8(
              a[mi], b[ni], acc[mi][ni], 0, 0, 0);
    }
  };

  stageAB(0, 0);
#pragma unroll 1
  for (int s = 0; s < 9; ++s) {           // 9 taps, BK=128 each
    const int s1 = s + 1;
    if (s1 < 9) stageAB(s1, s1 & 1);
    __builtin_amdgcn_sched_barrier(0);
    if (s1 < 9) { asm volatile("s_waitcnt vmcnt(8)" ::: "memory"); }
    else        { asm volatile("s_waitcnt vmcnt(0)" ::: "memory"); }
    __builtin_amdgcn_s_barrier();
    __builtin_amdgcn_sched_barrier(0);
    computeStep(s & 1);
    __builtin_amdgcn_sched_barrier(0);
    __builtin_amdgcn_s_barrier();
    __builtin_amdgcn_sched_barrier(0);
  }

  // ---- epilogue: +t, >> (-n), clamp, store int32 ----
  const int amin = aminp[0], amax = amaxp[0];
  int pbase[4];
#pragma unroll
  for (int ni = 0; ni < 4; ni++) {
    int pp = pb * 128 + wn * 64 + ni * 16 + lrow;
    int nn = pp / HW2;
    int hh = pp - nn * HW2;
    pbase[ni] = nn * OUT_NSTRIDE + hh;
  }
#pragma unroll
  for (int mi = 0; mi < 4; mi++) {
    int co0 = bm * 128 + wm * 64 + mi * 16 + ((l >> 4) << 2);
    const int4 t4 = *(const int4*)(tbias + co0);
    const int4 n4 = *(const int4*)(nshift + co0);
#pragma unroll
    for (int ni = 0; ni < 4; ni++) {
#pragma unroll
      for (int r = 0; r < 4; r++) {
        int tv = (r == 0) ? t4.x : (r == 1) ? t4.y : (r == 2) ? t4.z : t4.w;
        int nv = (r == 0) ? n4.x : (r == 1) ? n4.y : (r == 2) ? n4.z : n4.w;
        int v = acc[mi][ni][r] + tv;
        v = v >> (-nv);                       // arithmetic shift
        v = v < amin ? amin : (v > amax ? amax : v);
        out[pbase[ni] + (co0 + r) * HW2] = v;
      }
    }
  }
}

extern "C" void kernel_launch(void* const* d_in, const int* in_sizes, int n_in,
                              void* d_out, int out_size, void* d_ws, size_t ws_size,
                              hipStream_t stream) {
  const int* x      = (const int*)d_in[0];
  const int* w      = (const int*)d_in[1];
  const int* nshift = (const int*)d_in[2];
  const int* tbias  = (const int*)d_in[3];
  const int* aminp  = (const int*)d_in[4];
  const int* amaxp  = (const int*)d_in[5];
  int* out = (int*)d_out;

  char* xq = (char*)d_ws;
  char* wq = (char*)d_ws + WQ_OFF;
  char* zp = (char*)d_ws + ZP_OFF;

  hipLaunchKernelGGL(prep, dim3(2720), dim3(256), 0, stream, x, w, xq, wq, (int*)zp);
  hipLaunchKernelGGL(conv_mfma, dim3(1568), dim3(256), 0, stream,
                     xq, wq, zp, nshift, tbias, aminp, amaxp, out);
}